// Round 15
// baseline (61.976 us; speedup 1.0000x reference)
//
#include <hip/hip_runtime.h>
#include <hip/hip_bf16.h>

#define BB 16
#define SS 512
#define HH 768
#define RR 8
#define DD 512
#define CC 27
#define WW 256

typedef __attribute__((ext_vector_type(8))) short short8;
typedef __attribute__((ext_vector_type(4))) float f32x4;

union PKu { unsigned short us[8]; uint4 u4; short8 s8; };

__device__ __forceinline__ unsigned short f32_to_bf16_rne(float v) {
    unsigned int u = __float_as_uint(v);
    unsigned int r = u + 0x7fffu + ((u >> 16) & 1u);
    return (unsigned short)(r >> 16);
}
__device__ __forceinline__ float bf16_to_f32(unsigned short u) {
    return __uint_as_float(((unsigned int)u) << 16);
}
__device__ __forceinline__ void glds16(const void* g, void* l) {
    __builtin_amdgcn_global_load_lds(
        (const __attribute__((address_space(1))) unsigned int*)g,
        (__attribute__((address_space(3))) unsigned int*)l, 16, 0, 0);
}
__device__ __forceinline__ uint4 pack8(float4 f0, float4 f1) {
    PKu pk;
    pk.us[0] = f32_to_bf16_rne(f0.x);
    pk.us[1] = f32_to_bf16_rne(f0.y);
    pk.us[2] = f32_to_bf16_rne(f0.z);
    pk.us[3] = f32_to_bf16_rne(f0.w);
    pk.us[4] = f32_to_bf16_rne(f1.x);
    pk.us[5] = f32_to_bf16_rne(f1.y);
    pk.us[6] = f32_to_bf16_rne(f1.z);
    pk.us[7] = f32_to_bf16_rne(f1.w);
    return pk.u4;
}

// ---------------------------------------------------------------------------
// ws layout (bytes):
//   first_hidden : bf16[BB*WW][HH]  @ 0        (6291456)
//   w1t          : bf16[DD][HH]     @ 6291456  (786432)   top half only
//   w2t          : bf16[32][DD]     @ 7077888  (32768)
//   h_rel        : bf16[BB*RR][DD]  @ 7110656  (131072)
// ---------------------------------------------------------------------------

// K1: 337 blocks x 512 thr.
//  bid<256   : rel_logits + first-occurrence scatter (32 rows, 4-iter loop)
//  x<48      : w1t TOP transpose, 2 tiles/block (96 jobs)
//  x==48     : w2t
//  x<65      : per-batch zero absent rows (b = x-49)
//  x<81      : h_rel gemm (self-sufficient: A gathered from hidden,
//              B transposed from w1 bottom in-LDS), job = x-65
__global__ __launch_bounds__(512) void k_front(
    const float* __restrict__ hidden, const int* __restrict__ word_ids,
    const int* __restrict__ relpos, const float4* __restrict__ wrel4,
    const float* __restrict__ b_rel, const float* __restrict__ w1,
    const float* __restrict__ w2, float* __restrict__ out0,
    unsigned short* __restrict__ first_hidden,
    unsigned short* __restrict__ w1t, unsigned short* __restrict__ w2t,
    unsigned short* __restrict__ h_rel) {
    __shared__ __align__(16) unsigned char smem[25600];
    int bid = blockIdx.x, t = threadIdx.x;
    int wv = t >> 6, lane = t & 63;
    if (bid < 256) {
#pragma unroll
        for (int it = 0; it < 4; ++it) {
            int row = bid * 32 + it * 8 + wv;    // b*512+s
            const float4* hid4 = (const float4*)hidden + (size_t)row * (HH / 4);
            float4 v[3];
            float acc = 0.f;
#pragma unroll
            for (int j = 0; j < 3; ++j) {
                v[j] = hid4[j * 64 + lane];
                float4 w = wrel4[j * 64 + lane];
                acc += v[j].x * w.x + v[j].y * w.y + v[j].z * w.z + v[j].w * w.w;
            }
#pragma unroll
            for (int off = 32; off > 0; off >>= 1) acc += __shfl_xor(acc, off, 64);
            if (lane == 0) out0[row] = acc + b_rel[0];
            int wid = word_ids[row];
            int s = row & (SS - 1);
            int prev = (s == 0) ? -1 : word_ids[row - 1];
            if (wid != prev) {                   // first occurrence (wave-uniform)
                int b = row >> 9;
                unsigned short* dst = first_hidden + (size_t)(b * WW + wid) * HH;
#pragma unroll
                for (int j = 0; j < 3; ++j) {
                    union { unsigned short us[4]; uint2 u2; } pk;
                    pk.us[0] = f32_to_bf16_rne(v[j].x);
                    pk.us[1] = f32_to_bf16_rne(v[j].y);
                    pk.us[2] = f32_to_bf16_rne(v[j].z);
                    pk.us[3] = f32_to_bf16_rne(v[j].w);
                    *(uint2*)(dst + j * 256 + lane * 4) = pk.u2;
                }
            }
        }
        return;
    }
    int x = bid - 256;
    if (x < 48) {               // w1 top [768][512] f32 -> w1t [512][768] bf16
        unsigned short (*tile)[64][72] = (unsigned short(*)[64][72])smem;
        int half = t >> 8, tt = t & 255;
        int job = x * 2 + half;                  // 0..95
        int kt = job >> 3, nt = job & 7;         // kt 0..11
        int i = tt >> 2, j4 = (tt & 3) * 16;
        const float* src = w1 + (size_t)(kt * 64 + i) * DD + nt * 64 + j4;
#pragma unroll
        for (int v = 0; v < 4; ++v) {
            float4 f = *(const float4*)(src + v * 4);
            tile[half][i][j4 + v * 4 + 0] = f32_to_bf16_rne(f.x);
            tile[half][i][j4 + v * 4 + 1] = f32_to_bf16_rne(f.y);
            tile[half][i][j4 + v * 4 + 2] = f32_to_bf16_rne(f.z);
            tile[half][i][j4 + v * 4 + 3] = f32_to_bf16_rne(f.w);
        }
        __syncthreads();
        int jj = tt >> 2, cb = (tt & 3) * 16;
        union { unsigned short us[16]; uint4 u4[2]; } ov;
#pragma unroll
        for (int v = 0; v < 16; ++v) ov.us[v] = tile[half][cb + v][jj];
        unsigned short* dst = w1t + (size_t)(nt * 64 + jj) * HH + kt * 64 + cb;
        *(uint4*)(dst) = ov.u4[0];
        *(uint4*)(dst + 8) = ov.u4[1];
    } else if (x == 48) {       // w2 [512][27] -> w2t [32][512] bf16
        for (int idx = t; idx < 32 * DD; idx += 512) {
            int n = idx >> 9, k = idx & (DD - 1);
            float v = (n < CC) ? w2[(size_t)k * CC + n] : 0.f;
            w2t[n * DD + k] = f32_to_bf16_rne(v);
        }
    } else if (x < 65) {        // per-batch: zero absent rows
        int* pres = (int*)smem;
        int b = x - 49;
        if (t < WW) pres[t] = 0;
        __syncthreads();
        pres[word_ids[b * SS + t]] = 1;          // 512 threads cover all S
        __syncthreads();
        if (t < WW && !pres[t]) {                // thread t owns word t
            uint4 z = {0u, 0u, 0u, 0u};
            unsigned short* dst = first_hidden + (size_t)(b * WW + t) * HH;
#pragma unroll 4
            for (int c = 0; c < 96; ++c) *(uint4*)(dst + c * 8) = z;
        }
    } else {                    // h_rel gemm: 16 jobs (mh 0..1, nt 0..7)
        unsigned char* a_s = smem;                               // [64][8c] 8KB
        unsigned char* b_s = smem + 8192;                        // [64][8c] 8KB
        unsigned short (*tile)[72] = (unsigned short(*)[72])(smem + 16384); // 9216
        int job = x - 65;
        int mh = job >> 3, nt = job & 7;
        // A-stage mapping (1 chunk/thread per kt)
        int arow = t >> 3, as = t & 7;
        int grow = mh * 64 + arow;               // h_rel row = b*8+r
        int bb = grow >> 3, rr = grow & 7;
        int pos = relpos[bb * RR + rr];
        const float* aSrc = hidden + (size_t)(bb * SS + pos) * HH
                            + ((as ^ (arow & 7)) * 8);
        unsigned a_dst = (unsigned)(arow * 128 + as * 16);
        // B-tile stage mapping
        int bi = t >> 3, bc8 = (t & 7) * 8;
        // transpose mapping
        int tn = t >> 3, tsb = t & 7;
        int tsrc = tsb ^ (tn & 7);
        unsigned b_dst = (unsigned)(tn * 128 + tsb * 16);
        // MFMA mapping: 8 waves = 4 m-frags x 1, each wave 2 n-frags (wnh half)
        int wm = wv >> 1, wnh = wv & 1;
        int q = lane >> 4, r = lane & 15;
        int amr = wm * 16 + r;
        f32x4 acc[2];
        acc[0] = (f32x4){0.f, 0.f, 0.f, 0.f};
        acc[1] = (f32x4){0.f, 0.f, 0.f, 0.f};
        for (int kt = 0; kt < 12; ++kt) {
            {   // phase1: A gather+cvt, B f32 tile -> bf16
                float4 f0 = *(const float4*)(aSrc + kt * 64);
                float4 f1 = *(const float4*)(aSrc + kt * 64 + 4);
                *(uint4*)(a_s + a_dst) = pack8(f0, f1);
                const float* bsrc = w1 + (size_t)(HH + kt * 64 + bi) * DD
                                    + nt * 64 + bc8;
                float4 g0 = *(const float4*)(bsrc);
                float4 g1 = *(const float4*)(bsrc + 4);
                *(uint4*)(&tile[bi][bc8]) = pack8(g0, g1);
            }
            __syncthreads();
            {   // phase2: transpose tile -> b_s (pre-swizzled k-chunk gather)
                PKu pk;
#pragma unroll
                for (int v = 0; v < 8; ++v) pk.us[v] = tile[tsrc * 8 + v][tn];
                *(uint4*)(b_s + b_dst) = pk.u4;
            }
            __syncthreads();
#pragma unroll
            for (int ks = 0; ks < 2; ++ks) {    // phase3: MFMA
                int c8 = ks * 4 + q;
                short8 af = *(const short8*)(a_s + amr * 128 +
                                             ((c8 ^ (amr & 7)) << 4));
#pragma unroll
                for (int ni = 0; ni < 2; ++ni) {
                    int brow = wnh * 32 + ni * 16 + r;
                    short8 bf = *(const short8*)(b_s + brow * 128 +
                                                 ((c8 ^ (brow & 7)) << 4));
                    acc[ni] = __builtin_amdgcn_mfma_f32_16x16x32_bf16(
                        af, bf, acc[ni], 0, 0, 0);
                }
            }
            __syncthreads();
        }
#pragma unroll
        for (int ni = 0; ni < 2; ++ni) {
            int col = nt * 64 + wnh * 32 + ni * 16 + r;
#pragma unroll
            for (int reg = 0; reg < 4; ++reg) {
                int row = mh * 64 + wm * 16 + 4 * q + reg;
                h_rel[(size_t)row * DD + col] = f32_to_bf16_rne(acc[ni][reg]);
            }
        }
    }
}

// K2: merged h_word-gemm + role. 128 blocks x 512 thr, 152 KB LDS, 1 blk/CU.
// Block j owns 32 rows (b = j>>3, words (j&7)*32..+32): gemm A full-K in LDS,
// B = w1t top streamed dbuf BK=128; h_word tile stays in LDS; role fused.
__global__ __launch_bounds__(512) void k_tail(
    const unsigned short* __restrict__ first_hidden,
    const unsigned short* __restrict__ w1t,
    const unsigned short* __restrict__ w2t,
    const unsigned short* __restrict__ h_rel,
    const float* __restrict__ b1, const float* __restrict__ b2,
    float* __restrict__ out_role) {
    __shared__ __align__(16) unsigned char a_s[49152];   // [32][96c]
    __shared__ __align__(16) unsigned char b_s[32768];   // 2 x [64][16c]
    __shared__ __align__(16) unsigned char hw_s[32768];  // [32][64c] bf16 swz
    __shared__ __align__(16) unsigned char hr_s[8192];   // [8][64c] bf16 linear
    __shared__ __align__(16) unsigned char w2_s[32768];  // [32][64c] bf16 swz
    int j = blockIdx.x, t = threadIdx.x;
    int wv = t >> 6, lane = t & 63, q = lane >> 4, r = lane & 15;
    int b = j >> 3;
    int R0 = j * 32;           // global row base (first_hidden row)
    int w0 = (j & 7) * 32;     // word base within batch

    // ---- stage a_s full-K (6 chunks/thread, pre-swizzled source)
#pragma unroll
    for (int g = 0; g < 6; ++g) {
        int ci = g * 512 + t;
        int row = ci / 96, s = ci % 96;
        int sc = (s & ~7) | ((s & 7) ^ (row & 7));
        glds16((const unsigned char*)first_hidden + (size_t)(R0 + row) * 1536 + sc * 16,
               a_s + ci * 16);
    }
    // ---- stage w2_s (4/thread)
#pragma unroll
    for (int g = 0; g < 4; ++g) {
        int ci = g * 512 + t;
        int n = ci >> 6, s = ci & 63;
        int sc = (s & ~7) | ((s & 7) ^ (n & 7));
        glds16((const unsigned char*)w2t + (size_t)n * 1024 + sc * 16, w2_s + ci * 16);
    }
    // ---- stage hr (1/thread, linear)
    {
        int rr = t >> 6, c = t & 63;
        glds16((const unsigned char*)h_rel + (size_t)(b * RR + rr) * 1024 + c * 16,
               hr_s + t * 16);
    }
    // ---- B prologue (nt=0, kt=0): 2 chunks/thread
    {
        int bn = t >> 4, bs = t & 15;
        int sc = (bs & ~7) | ((bs & 7) ^ (bn & 7));
#pragma unroll
        for (int g = 0; g < 2; ++g) {
            int ci = g * 512 + t;
            int n = ci >> 4, s = ci & 15;
            int sc2 = (s & ~7) | ((s & 7) ^ (n & 7));
            glds16((const unsigned char*)w1t + (size_t)n * 1536 + sc2 * 16,
                   b_s + ci * 16);
        }
        (void)bn; (void)bs; (void)sc;
    }
    __syncthreads();

    // ---- gemm: 8 waves = 2 m-frags x 4 n-frags
    int wm = wv >> 2, wn = wv & 3;
    int amr = wm * 16 + r;
    int brow = wn * 16 + r;
    for (int nt = 0; nt < 8; ++nt) {
        f32x4 acc = (f32x4){0.f, 0.f, 0.f, 0.f};
        for (int kt = 0; kt < 6; ++kt) {
            int g = nt * 6 + kt;
            if (g < 47) {       // prefetch next B tile into other buffer
                int nk = kt + 1, nn = nt;
                if (nk == 6) { nk = 0; nn = nt + 1; }
                unsigned dst = ((g + 1) & 1) * 16384;
#pragma unroll
                for (int g2 = 0; g2 < 2; ++g2) {
                    int ci = g2 * 512 + t;
                    int n = ci >> 4, s = ci & 15;
                    int sc = (s & ~7) | ((s & 7) ^ (n & 7));
                    glds16((const unsigned char*)w1t +
                               (size_t)(nn * 64 + n) * 1536 + nk * 256 + sc * 16,
                           b_s + dst + ci * 16);
                }
            }
            unsigned bo = (g & 1) * 16384;
#pragma unroll
            for (int ks = 0; ks < 4; ++ks) {
                int c8 = ks * 4 + q;
                short8 af = *(const short8*)(a_s + amr * 1536 +
                                ((kt * 16 + (c8 ^ (amr & 7))) << 4));
                short8 bf = *(const short8*)(b_s + bo + brow * 256 +
                                ((c8 ^ (brow & 7)) << 4));
                acc = __builtin_amdgcn_mfma_f32_16x16x32_bf16(af, bf, acc, 0, 0, 0);
            }
            __syncthreads();
        }
        // write C fragment (+b1) into hw_s (role-compatible swizzle)
        int col = nt * 64 + wn * 16 + r;
        float b1v = b1[col];
        int chs = col >> 3, cb2 = (col & 7) * 2;
#pragma unroll
        for (int reg = 0; reg < 4; ++reg) {
            int row = wm * 16 + 4 * q + reg;
            *(unsigned short*)(hw_s + row * 1024 + ((chs ^ (row & 7)) << 4) + cb2) =
                f32_to_bf16_rne(acc[reg] + b1v);
        }
    }
    __syncthreads();

    // ---- role: 2 sub-tiles of 16 words, one r per wave
    int wl = lane & 15;
    int rr = wv;
#pragma unroll
    for (int sub = 0; sub < 2; ++sub) {
        f32x4 acc2[2];
        acc2[0] = (f32x4){0.f, 0.f, 0.f, 0.f};
        acc2[1] = (f32x4){0.f, 0.f, 0.f, 0.f};
        int hrow = sub * 16 + wl;
#pragma unroll 2
        for (int ks = 0; ks < 16; ++ks) {
            int c = 4 * ks + q;
            short8 bfr[2];
#pragma unroll
            for (int ni = 0; ni < 2; ++ni) {
                int n = ni * 16 + wl;
                bfr[ni] = *(const short8*)(w2_s + n * 1024 + ((c ^ (n & 7)) << 4));
            }
            PKu hw, hr;
            hw.u4 = *(const uint4*)(hw_s + hrow * 1024 + ((c ^ (hrow & 7)) << 4));
            hr.u4 = *(const uint4*)(hr_s + rr * 1024 + c * 16);
            PKu pk;
#pragma unroll
            for (int e = 0; e < 8; ++e)
                pk.us[e] = f32_to_bf16_rne(
                    fmaxf(bf16_to_f32(hw.us[e]) + bf16_to_f32(hr.us[e]), 0.f));
#pragma unroll
            for (int ni = 0; ni < 2; ++ni)
                acc2[ni] = __builtin_amdgcn_mfma_f32_16x16x32_bf16(
                    pk.s8, bfr[ni], acc2[ni], 0, 0, 0);
        }
#pragma unroll
        for (int ni = 0; ni < 2; ++ni) {
            int c = ni * 16 + wl;
            if (c < CC) {
#pragma unroll
                for (int reg = 0; reg < 4; ++reg) {
                    int wg = w0 + sub * 16 + 4 * q + reg;
                    out_role[(size_t)((b * RR + rr) * WW + wg) * CC + c] =
                        acc2[ni][reg] + b2[c];
                }
            }
        }
    }
}

extern "C" void kernel_launch(void* const* d_in, const int* in_sizes, int n_in,
                              void* d_out, int out_size, void* d_ws, size_t ws_size,
                              hipStream_t stream) {
    const float* hidden   = (const float*)d_in[0];
    const int*   word_ids = (const int*)d_in[1];
    const int*   relpos   = (const int*)d_in[2];
    const float* w_rel    = (const float*)d_in[3];
    const float* b_rel    = (const float*)d_in[4];
    const float* w1       = (const float*)d_in[5];
    const float* b1       = (const float*)d_in[6];
    const float* w2       = (const float*)d_in[7];
    const float* b2       = (const float*)d_in[8];

    float* out0 = (float*)d_out;                    // rel_logits [16*512]
    float* out1 = out0 + BB * SS;                   // role_logits [16*8*256*27]

    unsigned short* first_hidden = (unsigned short*)d_ws;
    unsigned short* w1t          = (unsigned short*)((char*)d_ws + 6291456);
    unsigned short* w2t          = (unsigned short*)((char*)d_ws + 7077888);
    unsigned short* h_rel        = (unsigned short*)((char*)d_ws + 7110656);

    k_front<<<337, 512, 0, stream>>>(
        hidden, word_ids, relpos, (const float4*)w_rel, b_rel, w1, w2,
        out0, first_hidden, w1t, w2t, h_rel);
    k_tail<<<128, 512, 0, stream>>>(
        first_hidden, w1t, w2t, h_rel, b1, b2, out1);
}

// Round 16
// 37.134 us; speedup vs baseline: 1.6690x; 1.6690x over previous
//
#include <hip/hip_runtime.h>
#include <hip/hip_bf16.h>

#define BB 16
#define SS 512
#define HH 768
#define RR 8
#define DD 512
#define CC 27
#define WW 256

typedef __attribute__((ext_vector_type(8))) short short8;
typedef __attribute__((ext_vector_type(4))) float f32x4;

union PKu { unsigned short us[8]; uint4 u4; short8 s8; };

__device__ __forceinline__ unsigned short f32_to_bf16_rne(float v) {
    unsigned int u = __float_as_uint(v);
    unsigned int r = u + 0x7fffu + ((u >> 16) & 1u);
    return (unsigned short)(r >> 16);
}
__device__ __forceinline__ float bf16_to_f32(unsigned short u) {
    return __uint_as_float(((unsigned int)u) << 16);
}

__device__ __forceinline__ void glds16(const void* g, void* l) {
    __builtin_amdgcn_global_load_lds(
        (const __attribute__((address_space(1))) unsigned int*)g,
        (__attribute__((address_space(3))) unsigned int*)l, 16, 0, 0);
}

// ---------------------------------------------------------------------------
// ws layout (bytes):
//   first_hidden : bf16[BB*WW][HH]   @ 0          (6291456)
//   rel_hidden   : bf16[BB*RR][HH]   @ 6291456    (196608)
//   w1t          : bf16[DD][2*HH]    @ 6488064    (1572864)
//   w2t          : bf16[32][DD]      @ 8060928    (32768)
//   h_word       : bf16[BB*WW][DD]   @ 8093696    (4194304)  (+b1 folded)
//   h_rel        : bf16[BB*RR][DD]   @ 12288000   (131072)
// ---------------------------------------------------------------------------

// K1 v2: 369 blocks x 512 thr.
//   bid<256   : rel_logits + first-occurrence scatter, 32 rows each (4-iter loop)
//   bid<352   : w1t transpose, 2 tiles/block (half-block per tile)
//   bid==352  : w2t
//   bid>=353  : per-batch zero absent rows + rel gather
__global__ __launch_bounds__(512) void k_front(
    const float* __restrict__ hidden, const int* __restrict__ word_ids,
    const int* __restrict__ relpos, const float4* __restrict__ wrel4,
    const float* __restrict__ b_rel, const float* __restrict__ w1,
    const float* __restrict__ w2, float* __restrict__ out0,
    unsigned short* __restrict__ first_hidden,
    unsigned short* __restrict__ rel_hidden,
    unsigned short* __restrict__ w1t, unsigned short* __restrict__ w2t) {
    int bid = blockIdx.x, t = threadIdx.x;
    int wv = t >> 6, lane = t & 63;
    if (bid < 256) {
#pragma unroll
        for (int it = 0; it < 4; ++it) {
            int row = bid * 32 + it * 8 + wv;    // b*512+s
            const float4* hid4 = (const float4*)hidden + (size_t)row * (HH / 4);
            float4 v[3];
            float acc = 0.f;
#pragma unroll
            for (int j = 0; j < 3; ++j) {
                v[j] = hid4[j * 64 + lane];
                float4 w = wrel4[j * 64 + lane];
                acc += v[j].x * w.x + v[j].y * w.y + v[j].z * w.z + v[j].w * w.w;
            }
#pragma unroll
            for (int off = 32; off > 0; off >>= 1) acc += __shfl_xor(acc, off, 64);
            if (lane == 0) out0[row] = acc + b_rel[0];
            int wid = word_ids[row];
            int s = row & (SS - 1);
            int prev = (s == 0) ? -1 : word_ids[row - 1];
            if (wid != prev) {                   // first occurrence (wave-uniform)
                int b = row >> 9;
                unsigned short* dst = first_hidden + (size_t)(b * WW + wid) * HH;
#pragma unroll
                for (int j = 0; j < 3; ++j) {
                    union { unsigned short us[4]; uint2 u2; } pk;
                    pk.us[0] = f32_to_bf16_rne(v[j].x);
                    pk.us[1] = f32_to_bf16_rne(v[j].y);
                    pk.us[2] = f32_to_bf16_rne(v[j].z);
                    pk.us[3] = f32_to_bf16_rne(v[j].w);
                    *(uint2*)(dst + j * 256 + lane * 4) = pk.u2;
                }
            }
        }
        return;
    }
    int x = bid - 256;
    if (x < 96) {               // w1 [1536][512] f32 -> w1t [512][1536] bf16
        __shared__ unsigned short tile[2][64][72];
        int half = t >> 8, tt = t & 255;
        int job = x * 2 + half;                  // 0..191
        int kt = job >> 3, nt = job & 7;
        int i = tt >> 2, j4 = (tt & 3) * 16;
        const float* src = w1 + (size_t)(kt * 64 + i) * DD + nt * 64 + j4;
#pragma unroll
        for (int v = 0; v < 4; ++v) {
            float4 f = *(const float4*)(src + v * 4);
            tile[half][i][j4 + v * 4 + 0] = f32_to_bf16_rne(f.x);
            tile[half][i][j4 + v * 4 + 1] = f32_to_bf16_rne(f.y);
            tile[half][i][j4 + v * 4 + 2] = f32_to_bf16_rne(f.z);
            tile[half][i][j4 + v * 4 + 3] = f32_to_bf16_rne(f.w);
        }
        __syncthreads();
        int jj = tt >> 2, cb = (tt & 3) * 16;
        union { unsigned short us[16]; uint4 u4[2]; } ov;
#pragma unroll
        for (int v = 0; v < 16; ++v) ov.us[v] = tile[half][cb + v][jj];
        unsigned short* dst = w1t + (size_t)(nt * 64 + jj) * (2 * HH) + kt * 64 + cb;
        *(uint4*)(dst) = ov.u4[0];
        *(uint4*)(dst + 8) = ov.u4[1];
    } else if (x == 96) {       // w2 [512][27] -> w2t [32][512] bf16
        for (int idx = t; idx < 32 * DD; idx += 512) {
            int n = idx >> 9, k = idx & (DD - 1);
            float v = (n < CC) ? w2[(size_t)k * CC + n] : 0.f;
            w2t[n * DD + k] = f32_to_bf16_rne(v);
        }
    } else {                    // per-batch: zero absent rows + rel gather
        __shared__ int pres[WW];
        int b = x - 97;
        if (t < WW) pres[t] = 0;
        __syncthreads();
        pres[word_ids[b * SS + t]] = 1;          // 512 threads cover all S
        __syncthreads();
        if (t < WW && !pres[t]) {                // thread t owns word t
            uint4 z = {0u, 0u, 0u, 0u};
            unsigned short* dst = first_hidden + (size_t)(b * WW + t) * HH;
#pragma unroll 4
            for (int c = 0; c < 96; ++c) *(uint4*)(dst + c * 8) = z;
        }
        for (int idx = t; idx < RR * 96; idx += 512) {
            int rr = idx / 96, c = idx % 96;
            int pos = relpos[b * RR + rr];
            const float* srow = hidden + (size_t)(b * SS + pos) * HH + c * 8;
            PKu pk;
#pragma unroll
            for (int e = 0; e < 8; ++e) pk.us[e] = f32_to_bf16_rne(srow[e]);
            *(uint4*)(rel_hidden + (size_t)(b * RR + rr) * HH + c * 8) = pk.u4;
        }
    }
}

// K2: C = A @ w1t[:, kbase:kbase+768]^T, bf16 MFMA.
// 64x64 tile, BK=64, dbuf LDS (32KB -> >=2 blocks/CU), 4 waves 2x2.
__global__ __launch_bounds__(256) void k_gemm(
    const unsigned short* __restrict__ first_hidden,
    const unsigned short* __restrict__ rel_hidden,
    const unsigned short* __restrict__ w1t, const float* __restrict__ b1,
    unsigned short* __restrict__ h_word, unsigned short* __restrict__ h_rel) {
    __shared__ __align__(16) unsigned char a_s[16384];  // 2 x [64 rows][128B]
    __shared__ __align__(16) unsigned char b_s[16384];  // 2 x [64 rows][128B]
    int bid = blockIdx.x;
    int nt, m0;
    bool isw;
    if (bid < 512) {
        int xcd = bid & 7, k = bid >> 3;     // block bid -> XCD bid%8
        int mt = xcd + 8 * (k & 7);          // same-mt jobs share the XCD
        nt = k >> 3;
        isw = true;
        m0 = mt * 64;
    } else {
        int jj = bid - 512;
        isw = false;
        m0 = (jj >> 3) * 64;
        nt = jj & 7;
    }
    const unsigned short* A = isw ? first_hidden : rel_hidden;
    unsigned short* C = isw ? h_word : h_rel;
    int kbase = isw ? 0 : HH;
    int t = threadIdx.x;
    int wv = t >> 6, lane = t & 63;
    int wr = wv >> 1, wc = wv & 1;
    int q = lane >> 4, r = lane & 15;

    const unsigned char* aP[2];
    const unsigned char* bP[2];
    unsigned lofa[2], lofb[2];
#pragma unroll
    for (int g = 0; g < 2; ++g) {               // A/B: 64 rows x 8 chunks = 512 each
        int ci = g * 256 + t;
        int row = ci >> 3, ch = ci & 7;
        int sc = ch ^ (row & 7);                 // inverse-swizzled source chunk
        aP[g] = (const unsigned char*)A + (size_t)(m0 + row) * (HH * 2) + sc * 16;
        lofa[g] = ci * 16;
        bP[g] = (const unsigned char*)w1t + (size_t)(nt * 64 + row) * (2 * HH * 2)
                + (size_t)kbase * 2 + sc * 16;
        lofb[g] = ci * 16;
    }
    int arow[2], brow[2];
#pragma unroll
    for (int mi = 0; mi < 2; ++mi) arow[mi] = wr * 32 + mi * 16 + r;
#pragma unroll
    for (int ni = 0; ni < 2; ++ni) brow[ni] = wc * 32 + ni * 16 + r;

    f32x4 acc[2][2];
#pragma unroll
    for (int mi = 0; mi < 2; ++mi)
#pragma unroll
        for (int ni = 0; ni < 2; ++ni) acc[mi][ni] = (f32x4){0.f, 0.f, 0.f, 0.f};

    // prologue: stage kt=0 into buf 0
#pragma unroll
    for (int g = 0; g < 2; ++g) glds16(aP[g], a_s + lofa[g]);
#pragma unroll
    for (int g = 0; g < 2; ++g) glds16(bP[g], b_s + lofb[g]);
    __syncthreads();

    for (int kt = 0; kt < 12; ++kt) {
        if (kt < 11) {         // prefetch kt+1 into other buffer (hidden by MFMA)
            unsigned nb = ((kt + 1) & 1) * 8192;
#pragma unroll
            for (int g = 0; g < 2; ++g) glds16(aP[g] + (kt + 1) * 128, a_s + nb + lofa[g]);
#pragma unroll
            for (int g = 0; g < 2; ++g) glds16(bP[g] + (kt + 1) * 128, b_s + nb + lofb[g]);
        }
        unsigned bo = (kt & 1) * 8192;
#pragma unroll
        for (int ks = 0; ks < 2; ++ks) {
            int c = ks * 4 + q;
            short8 bfr[2];
#pragma unroll
            for (int ni = 0; ni < 2; ++ni)
                bfr[ni] = *(const short8*)(b_s + bo + brow[ni] * 128 +
                            ((c ^ (brow[ni] & 7)) << 4));
#pragma unroll
            for (int mi = 0; mi < 2; ++mi) {
                short8 af = *(const short8*)(a_s + bo + arow[mi] * 128 +
                            ((c ^ (arow[mi] & 7)) << 4));
                acc[mi][0] = __builtin_amdgcn_mfma_f32_16x16x32_bf16(
                    af, bfr[0], acc[mi][0], 0, 0, 0);
                acc[mi][1] = __builtin_amdgcn_mfma_f32_16x16x32_bf16(
                    af, bfr[1], acc[mi][1], 0, 0, 0);
            }
        }
        __syncthreads();
    }
    float bias[2];
#pragma unroll
    for (int ni = 0; ni < 2; ++ni) {
        int n = nt * 64 + wc * 32 + ni * 16 + r;
        bias[ni] = isw ? b1[n] : 0.f;
    }
#pragma unroll
    for (int mi = 0; mi < 2; ++mi) {
        int m = m0 + wr * 32 + mi * 16 + q * 4;
#pragma unroll
        for (int ni = 0; ni < 2; ++ni) {
            int n = nt * 64 + wc * 32 + ni * 16 + r;
#pragma unroll
            for (int reg = 0; reg < 4; ++reg)
                C[(size_t)(m + reg) * DD + n] =
                    f32_to_bf16_rne(acc[mi][ni][reg] + bias[ni]);
        }
    }
}

// K3: role_logits = relu(h_word'[b,w,:]+h_rel[b,r,:]) @ w2 + b2 via MFMA.
// 512 thr = 8 waves (one r each). LDS 64KB -> 2 blocks/CU.
__global__ __launch_bounds__(512) void k_role(
    const unsigned short* __restrict__ h_word, const unsigned short* __restrict__ h_rel,
    const unsigned short* __restrict__ w2t, const float* __restrict__ b2,
    float* __restrict__ out_role) {
    int wt = blockIdx.x;   // 0..15
    int b  = blockIdx.y;   // 0..15
    int t  = threadIdx.x;  // 512
    __shared__ __align__(16) unsigned char hw_s[16384];  // [16 w][512] bf16 swz
    __shared__ float hr_s[RR][DD];                       // 16 KB f32 linear
    __shared__ __align__(16) unsigned char w2_s[32768];  // [32 n][512] bf16 swz
    int wv = t >> 6, lane = t & 63;
#pragma unroll
    for (int i = 0; i < 2; ++i) {
        int row = wv * 2 + i;
        const unsigned short* src = h_word +
            (size_t)(b * WW + wt * 16 + row) * DD + ((lane ^ (row & 7)) * 8);
        glds16(src, hw_s + row * 1024 + lane * 16);
    }
#pragma unroll
    for (int i = 0; i < 4; ++i) {
        int row = wv * 4 + i;
        const unsigned short* src = w2t + row * DD + ((lane ^ (row & 7)) * 8);
        glds16(src, w2_s + row * 1024 + lane * 16);
    }
    {
        int rr = wv, c = lane;
        PKu hv;
        hv.u4 = *(const uint4*)(h_rel + (size_t)(b * RR + rr) * DD + c * 8);
        float4 o0, o1;
        o0.x = bf16_to_f32(hv.us[0]); o0.y = bf16_to_f32(hv.us[1]);
        o0.z = bf16_to_f32(hv.us[2]); o0.w = bf16_to_f32(hv.us[3]);
        o1.x = bf16_to_f32(hv.us[4]); o1.y = bf16_to_f32(hv.us[5]);
        o1.z = bf16_to_f32(hv.us[6]); o1.w = bf16_to_f32(hv.us[7]);
        *(float4*)&hr_s[rr][c * 8]     = o0;
        *(float4*)&hr_s[rr][c * 8 + 4] = o1;
    }
    __syncthreads();
    int q = lane >> 4, wl = lane & 15;
    int rr = wv;
    unsigned wlx = (wl & 7) << 4;
    f32x4 acc[2];
#pragma unroll
    for (int ni = 0; ni < 2; ++ni) acc[ni] = (f32x4){0.f, 0.f, 0.f, 0.f};

#pragma unroll 2
    for (int ks = 0; ks < DD / 32; ++ks) {
        int c = 4 * ks + q;
        short8 bfr[2];
#pragma unroll
        for (int ni = 0; ni < 2; ++ni) {
            int n = ni * 16 + wl;
            bfr[ni] = *(const short8*)(w2_s + n * 1024 + ((c ^ (n & 7)) << 4));
        }
        PKu hw;
        hw.u4 = *(const uint4*)(hw_s + wl * 1024 + ((unsigned)(c << 4) ^ wlx));
        const float* hrp = &hr_s[rr][ks * 32 + q * 8];
        float4 h0 = *(const float4*)(hrp);
        float4 h1 = *(const float4*)(hrp + 4);
        PKu pk;
        pk.us[0] = f32_to_bf16_rne(fmaxf(bf16_to_f32(hw.us[0]) + h0.x, 0.f));
        pk.us[1] = f32_to_bf16_rne(fmaxf(bf16_to_f32(hw.us[1]) + h0.y, 0.f));
        pk.us[2] = f32_to_bf16_rne(fmaxf(bf16_to_f32(hw.us[2]) + h0.z, 0.f));
        pk.us[3] = f32_to_bf16_rne(fmaxf(bf16_to_f32(hw.us[3]) + h0.w, 0.f));
        pk.us[4] = f32_to_bf16_rne(fmaxf(bf16_to_f32(hw.us[4]) + h1.x, 0.f));
        pk.us[5] = f32_to_bf16_rne(fmaxf(bf16_to_f32(hw.us[5]) + h1.y, 0.f));
        pk.us[6] = f32_to_bf16_rne(fmaxf(bf16_to_f32(hw.us[6]) + h1.z, 0.f));
        pk.us[7] = f32_to_bf16_rne(fmaxf(bf16_to_f32(hw.us[7]) + h1.w, 0.f));
#pragma unroll
        for (int ni = 0; ni < 2; ++ni)
            acc[ni] = __builtin_amdgcn_mfma_f32_16x16x32_bf16(
                pk.s8, bfr[ni], acc[ni], 0, 0, 0);
    }
#pragma unroll
    for (int ni = 0; ni < 2; ++ni) {
        int c = ni * 16 + wl;
        if (c < CC) {
#pragma unroll
            for (int reg = 0; reg < 4; ++reg) {
                int wg = wt * 16 + 4 * q + reg;
                out_role[(size_t)((b * RR + rr) * WW + wg) * CC + c] =
                    acc[ni][reg] + b2[c];
            }
        }
    }
}

extern "C" void kernel_launch(void* const* d_in, const int* in_sizes, int n_in,
                              void* d_out, int out_size, void* d_ws, size_t ws_size,
                              hipStream_t stream) {
    const float* hidden   = (const float*)d_in[0];
    const int*   word_ids = (const int*)d_in[1];
    const int*   relpos   = (const int*)d_in[2];
    const float* w_rel    = (const float*)d_in[3];
    const float* b_rel    = (const float*)d_in[4];
    const float* w1       = (const float*)d_in[5];
    const float* b1       = (const float*)d_in[6];
    const float* w2       = (const float*)d_in[7];
    const float* b2       = (const float*)d_in[8];

    float* out0 = (float*)d_out;                    // rel_logits [16*512]
    float* out1 = out0 + BB * SS;                   // role_logits [16*8*256*27]

    unsigned short* first_hidden = (unsigned short*)d_ws;
    unsigned short* rel_hidden   = (unsigned short*)((char*)d_ws + 6291456);
    unsigned short* w1t          = (unsigned short*)((char*)d_ws + 6488064);
    unsigned short* w2t          = (unsigned short*)((char*)d_ws + 8060928);
    unsigned short* h_word       = (unsigned short*)((char*)d_ws + 8093696);
    unsigned short* h_rel        = (unsigned short*)((char*)d_ws + 12288000);

    k_front<<<369, 512, 0, stream>>>(
        hidden, word_ids, relpos, (const float4*)w_rel, b_rel, w1, w2,
        out0, first_hidden, rel_hidden, w1t, w2t);
    k_gemm<<<528, 256, 0, stream>>>(
        first_hidden, rel_hidden, w1t, b1, h_word, h_rel);
    k_role<<<dim3(WW / 16, BB), 512, 0, stream>>>(h_word, h_rel, w2t, b2, out1);
}